// Round 22
// baseline (3445.007 us; speedup 1.0000x reference)
//
#include <hip/hip_runtime.h>
#include <math.h>

// 3-layer LSTM (H=64, T=512, B=2048, Din=16), R21: R20 zeroing fix.
// R20 NaN root cause: xp[2][4*64] = 256 u32 but the zero loop covered only
// 128 u32 -> x-plane cols 16-63 (never written for layer-0, Din=16) were
// uninitialized LDS; NaN * 0-weight = NaN inside the MFMA. R21 zeroes all
// planes fully; everything else identical to R20:
//   CB=4, grid=512 -> 2 independent blocks/CU = 8 waves/SIMD (TLP overlap);
//   waves_per_eu(8,8) pins the <=64-VGPR budget; wave roles 0-3=L0 cells,
//   4-7=L2 cells, 8-11=L1 cells, 12=x staging.
// Arithmetic identical to R19 -> absmax must be exactly 9.765625e-4.

#define T_STEPS 512
#define BATCH   2048
#define HID     64
#define NG      256
#define CB      4
#define NTHR    1024

typedef __attribute__((ext_vector_type(8))) _Float16 f16x8;
typedef __attribute__((ext_vector_type(4))) float f32x4;

__device__ __forceinline__ float sigm(float z) { return 1.0f / (1.0f + __expf(-z)); }
__device__ __forceinline__ float tanh_f(float z) {
    z = fminf(15.0f, fmaxf(-15.0f, z));
    const float e = __expf(2.0f * z);
    return (e - 1.0f) / (e + 1.0f);
}
// 4-row 128B/row fp16 plane, XOR-swizzled 16B units; rows alias &3
__device__ __forceinline__ int pa(int row, int u8) {
    row &= 3;
    return row * 128 + ((u8 ^ row) << 4);
}
__device__ __forceinline__ void pwr(_Float16* p, int row, int u, _Float16 v) {
    *(_Float16*)((char*)p + pa(row, u >> 3) + (u & 7) * 2) = v;
}
__device__ __forceinline__ f16x8 prd(const _Float16* p, int row, int u8) {
    return *(const f16x8*)((const char*)p + pa(row, u8));
}

#define MFMA16(A, B, C)  __builtin_amdgcn_mfma_f32_16x16x32_f16((A), (B), (C), 0, 0, 0)

__device__ __forceinline__ f16x8 ldw16(const float* p) {
    const float4 a = *(const float4*)p;
    const float4 b = *(const float4*)(p + 4);
    f16x8 w;
    w[0]=(_Float16)a.x; w[1]=(_Float16)a.y; w[2]=(_Float16)a.z; w[3]=(_Float16)a.w;
    w[4]=(_Float16)b.x; w[5]=(_Float16)b.y; w[6]=(_Float16)b.z; w[7]=(_Float16)b.w;
    return w;
}

// gts writeout: only C rows 0-3 are real (CB=4) -> lanes 0-15 write
#define GTS_STORE(GT, G) do {                                                 \
    if ((lane >> 4) == 0) {                                                   \
        float* gd = &(GT)[ncol];                                              \
        gd[0]      = (G)[0];                                                  \
        gd[NG]     = (G)[1];                                                  \
        gd[2 * NG] = (G)[2];                                                  \
        gd[3 * NG] = (G)[3];                                                  \
    }                                                                         \
} while (0)

// cell update: reads gts row, updates CST, writes h to PLANE as fp16
#define CELL(GT, CST, PLANE, B_, U_, HOUT_) do {                              \
    const float* gsrc = &(GT)[(B_) * NG + (U_)];                              \
    const float gi = gsrc[0];                                                 \
    const float gf = gsrc[64];                                                \
    const float gg = gsrc[128];                                               \
    const float go = gsrc[192];                                               \
    CST = sigm(gf) * CST + sigm(gi) * tanh_f(gg);                             \
    HOUT_ = sigm(go) * tanh_f(CST);                                           \
    pwr((PLANE), (B_), (U_), (_Float16)HOUT_);                                \
} while (0)

__global__
__attribute__((amdgpu_flat_work_group_size(NTHR, NTHR),
               amdgpu_waves_per_eu(8, 8)))
void lstm3_fused(
    const float* __restrict__ x0,    // [B][T][16] fp32
    const float* __restrict__ Wih0,  // [256][16]
    const float* __restrict__ Whh0,  // [256][64]
    const float* __restrict__ bih0, const float* __restrict__ bhh0,
    const float* __restrict__ Wih1,  // [256][64]
    const float* __restrict__ Whh1,
    const float* __restrict__ bih1, const float* __restrict__ bhh1,
    const float* __restrict__ Wih2,
    const float* __restrict__ Whh2,
    const float* __restrict__ bih2, const float* __restrict__ bhh2,
    const float* __restrict__ Wout,  // [7][64]
    const float* __restrict__ bout,  // [7]
    float* __restrict__ out)         // [B][7]
{
    __shared__ __attribute__((aligned(16))) _Float16 xp[2][4 * 64];
    __shared__ __attribute__((aligned(16))) _Float16 h0p[4 * 64];
    __shared__ __attribute__((aligned(16))) _Float16 h1p[4 * 64];
    __shared__ __attribute__((aligned(16))) _Float16 h2p[4 * 64];
    __shared__ __attribute__((aligned(16))) float gt0[4 * NG];
    __shared__ __attribute__((aligned(16))) float gt1[4 * NG];
    __shared__ __attribute__((aligned(16))) float gt2[4 * NG];
    __shared__ __attribute__((aligned(16))) float hf[4 * HID];

    const int tid  = threadIdx.x;
    const int lane = tid & 63;
    const int wid  = tid >> 6;          // 0..15: N-tile index
    const int ncol = wid * 16 + (lane & 15);
    const int ksub = (lane >> 4) & 3;   // k-subgroup of 8
    const int arow = lane & 15;
    const int b0   = blockIdx.x * CB;

    // ---- weight fragments: 1-term fp16, all 3 layers resident ----
    const int k0 = ksub * 8;
    f16x8 WI0 = {0,0,0,0,0,0,0,0};
    if (k0 < 16) WI0 = ldw16(Wih0 + ncol * 16 + k0);
    const f16x8 WH00 = ldw16(Whh0 + ncol * HID + k0);
    const f16x8 WH01 = ldw16(Whh0 + ncol * HID + 32 + k0);
    const f16x8 WI10 = ldw16(Wih1 + ncol * HID + k0);
    const f16x8 WI11 = ldw16(Wih1 + ncol * HID + 32 + k0);
    const f16x8 WH10 = ldw16(Whh1 + ncol * HID + k0);
    const f16x8 WH11 = ldw16(Whh1 + ncol * HID + 32 + k0);
    const f16x8 WI20 = ldw16(Wih2 + ncol * HID + k0);
    const f16x8 WI21 = ldw16(Wih2 + ncol * HID + 32 + k0);
    const f16x8 WH20 = ldw16(Whh2 + ncol * HID + k0);
    const f16x8 WH21 = ldw16(Whh2 + ncol * HID + 32 + k0);
    const float bias0 = bih0[ncol] + bhh0[ncol];
    const float bias1 = bih1[ncol] + bhh1[ncol];
    const float bias2 = bih2[ncol] + bhh2[ncol];

    // ---- zero planes (FIX): xp = 256 u32; h planes = 128 u32 each ----
    if (tid < 256) ((unsigned*)xp)[tid] = 0;
    else if (tid < 384) ((unsigned*)h0p)[tid - 256] = 0;
    else if (tid < 512) ((unsigned*)h1p)[tid - 384] = 0;
    else if (tid < 640) ((unsigned*)h2p)[tid - 512] = 0;
    __syncthreads();

    // ---- prologue: stage x(0)->buf0, x(1)->buf1 (wave 12: tid 768-831) ----
    const int sidx = tid - 768;
    const int sbx = (sidx >> 4) & 3, sk = sidx & 15;
    const bool isStg = (tid >= 768) && (tid < 832);
    if (isStg) {
        #pragma unroll
        for (int s = 0; s < 2; ++s) {
            const float v = x0[(size_t)(b0 + sbx) * (T_STEPS * 16) + s * 16 + sk];
            pwr(xp[s], sbx, sk, (_Float16)v);
        }
    }
    __syncthreads();

    float cst = 0.0f;   // one cell per thread (waves 0-11)
    const float* xin = x0 + (size_t)(b0 + sbx) * (T_STEPS * 16) + 2 * 16 + sk;

    for (int it = 0; it < T_STEPS + 2; ++it) {
        const bool a0 = it < T_STEPS;
        const bool a1 = (it >= 1) && (it < T_STEPS + 1);
        const bool a2 = it >= 2;

        // ---- staging load issue: x(it+2) ----
        float pxn = 0.0f;
        if (isStg && it + 2 < T_STEPS) pxn = *xin;

        // ================= Phase A: MFMA for 3 layers =================
        {
            const f16x8 a00 = prd(h0p, arow, ksub);
            const f16x8 a01 = prd(h0p, arow, 4 + ksub);
            if (a0) {
                const f16x8 ax = prd(xp[it & 1], arow, ksub);
                f32x4 G = {bias0, bias0, bias0, bias0};
                G = MFMA16(ax, WI0, G);
                G = MFMA16(a00, WH00, G);
                G = MFMA16(a01, WH01, G);
                GTS_STORE(gt0, G);
            }
            const f16x8 a10 = prd(h1p, arow, ksub);
            const f16x8 a11 = prd(h1p, arow, 4 + ksub);
            if (a1) {
                f32x4 G = {bias1, bias1, bias1, bias1};
                G = MFMA16(a00, WI10, G);
                G = MFMA16(a01, WI11, G);
                G = MFMA16(a10, WH10, G);
                G = MFMA16(a11, WH11, G);
                GTS_STORE(gt1, G);
            }
            if (a2) {
                const f16x8 a20 = prd(h2p, arow, ksub);
                const f16x8 a21 = prd(h2p, arow, 4 + ksub);
                f32x4 G = {bias2, bias2, bias2, bias2};
                G = MFMA16(a10, WI20, G);
                G = MFMA16(a11, WI21, G);
                G = MFMA16(a20, WH20, G);
                G = MFMA16(a21, WH21, G);
                GTS_STORE(gt2, G);
            }
        }
        __syncthreads();

        // ================= Phase B: cells + staging =================
        if (tid < 256) {                      // waves 0-3: L0 cells
            const int b = tid >> 6, u = tid & 63;
            float h;
            if (a0) CELL(gt0, cst, h0p, b, u, h);
        } else if (tid < 512) {               // waves 4-7: L2 cells
            const int b = (tid - 256) >> 6, u = tid & 63;
            float h;
            if (a2) {
                CELL(gt2, cst, h2p, b, u, h);
                if (it == T_STEPS + 1) hf[b * HID + u] = h;
            }
        } else if (tid < 768) {               // waves 8-11: L1 cells
            const int b = (tid - 512) >> 6, u = tid & 63;
            float h;
            if (a1) CELL(gt1, cst, h1p, b, u, h);
        } else {                              // wave 12: x staging
            if (isStg && it + 2 < T_STEPS) pwr(xp[it & 1], sbx, sk, (_Float16)pxn);
        }
        __syncthreads();

        xin += 16;
    }

    // ---- head: out = h2[T-1] @ Wout^T + bout ----
    if (tid < 7 * CB) {
        const int b = tid / 7, o = tid % 7;
        float a = bout[o];
        #pragma unroll
        for (int k = 0; k < HID; ++k)
            a = fmaf(hf[b * HID + k], Wout[o * HID + k], a);
        out[(b0 + b) * 7 + o] = a;
    }
}

extern "C" void kernel_launch(void* const* d_in, const int* in_sizes, int n_in,
                              void* d_out, int out_size, void* d_ws, size_t ws_size,
                              hipStream_t stream) {
    const float* x    = (const float*)d_in[0];
    const float* Wih0 = (const float*)d_in[1];
    const float* Whh0 = (const float*)d_in[2];
    const float* bih0 = (const float*)d_in[3];
    const float* bhh0 = (const float*)d_in[4];
    const float* Wih1 = (const float*)d_in[5];
    const float* Whh1 = (const float*)d_in[6];
    const float* bih1 = (const float*)d_in[7];
    const float* bhh1 = (const float*)d_in[8];
    const float* Wih2 = (const float*)d_in[9];
    const float* Whh2 = (const float*)d_in[10];
    const float* bih2 = (const float*)d_in[11];
    const float* bhh2 = (const float*)d_in[12];
    const float* Wout = (const float*)d_in[13];
    const float* bout = (const float*)d_in[14];
    float* out = (float*)d_out;

    lstm3_fused<<<dim3(BATCH / CB), dim3(NTHR), 0, stream>>>(
        x, Wih0, Whh0, bih0, bhh0,
        Wih1, Whh1, bih1, bhh1,
        Wih2, Whh2, bih2, bhh2,
        Wout, bout, out);
}

// Round 23
// 633.736 us; speedup vs baseline: 5.4360x; 5.4360x over previous
//
#include <hip/hip_runtime.h>
#include <math.h>

// 3-layer LSTM (H=64, T=512, B=2048, Din=16), R22: R19 + fast cell math.
// R21 post-mortem: waves_per_eu(8,8) capped VGPR at 32 < 44 weight frags ->
// full spill (FETCH 11 GB, 3445us). 2-blocks/CU is structurally dead for the
// fused kernel (needs ~95 VGPRs). Revert to R19 (874us, VGPR=64, 4 waves/EU).
// R22 single change: cell divisions -> v_rcp_f32 approx (~1 ulp).
//   sigm(z) = rcp(1+exp(-z));  tanh(z) = 1 - 2*rcp(e^{2z}+1)
// Without fast-math each fp32 '/' was a ~12-instr div sequence; 5 divs/cell
// ~= 60 VALU instrs of division. Cell drops ~110 -> ~35 instrs.
// Everything else byte-identical to R19. absmax ~9.77e-4 (rcp err ~1e-7).

#define T_STEPS 512
#define BATCH   2048
#define HID     64
#define NG      256
#define CB      8
#define NTHR    1024

typedef __attribute__((ext_vector_type(8))) _Float16 f16x8;
typedef __attribute__((ext_vector_type(4))) float f32x4;

__device__ __forceinline__ float rcpf(float x) { return __builtin_amdgcn_rcpf(x); }
__device__ __forceinline__ float sigm(float z) {
    return rcpf(1.0f + __expf(-z));
}
__device__ __forceinline__ float tanh_f(float z) {
    z = fminf(15.0f, fmaxf(-15.0f, z));
    return 1.0f - 2.0f * rcpf(__expf(2.0f * z) + 1.0f);
}
// 8-row 128B/row fp16 plane, XOR-swizzled 16B units; rows alias &7
__device__ __forceinline__ int pa(int row, int u8) {
    row &= 7;
    return row * 128 + ((u8 ^ row) << 4);
}
__device__ __forceinline__ void pwr(_Float16* p, int row, int u, _Float16 v) {
    *(_Float16*)((char*)p + pa(row, u >> 3) + (u & 7) * 2) = v;
}
__device__ __forceinline__ f16x8 prd(const _Float16* p, int row, int u8) {
    return *(const f16x8*)((const char*)p + pa(row, u8));
}

#define MFMA16(A, B, C)  __builtin_amdgcn_mfma_f32_16x16x32_f16((A), (B), (C), 0, 0, 0)

__device__ __forceinline__ f16x8 ldw16(const float* p) {
    const float4 a = *(const float4*)p;
    const float4 b = *(const float4*)(p + 4);
    f16x8 w;
    w[0]=(_Float16)a.x; w[1]=(_Float16)a.y; w[2]=(_Float16)a.z; w[3]=(_Float16)a.w;
    w[4]=(_Float16)b.x; w[5]=(_Float16)b.y; w[6]=(_Float16)b.z; w[7]=(_Float16)b.w;
    return w;
}

// gts writeout: C rows 8-15 are dups (planes alias row&7) -> lanes 0-31 write
#define GTS_STORE(GT, G) do {                                                 \
    if ((lane >> 4) < 2) {                                                    \
        float* gd = &(GT)[(lane >> 4) * 4 * NG + ncol];                       \
        gd[0]      = (G)[0];                                                  \
        gd[NG]     = (G)[1];                                                  \
        gd[2 * NG] = (G)[2];                                                  \
        gd[3 * NG] = (G)[3];                                                  \
    }                                                                         \
} while (0)

// cell update: reads gts row, updates CST, writes h to PLANE as fp16
#define CELL(GT, CST, PLANE, B_, U_, HOUT_) do {                              \
    const float* gsrc = &(GT)[(B_) * NG + (U_)];                              \
    const float gi = gsrc[0];                                                 \
    const float gf = gsrc[64];                                                \
    const float gg = gsrc[128];                                               \
    const float go = gsrc[192];                                               \
    CST = sigm(gf) * CST + sigm(gi) * tanh_f(gg);                             \
    HOUT_ = sigm(go) * tanh_f(CST);                                           \
    pwr((PLANE), (B_), (U_), (_Float16)HOUT_);                                \
} while (0)

__global__
__attribute__((amdgpu_flat_work_group_size(NTHR, NTHR),
               amdgpu_waves_per_eu(4, 4)))
void lstm3_fused(
    const float* __restrict__ x0,    // [B][T][16] fp32
    const float* __restrict__ Wih0,  // [256][16]
    const float* __restrict__ Whh0,  // [256][64]
    const float* __restrict__ bih0, const float* __restrict__ bhh0,
    const float* __restrict__ Wih1,  // [256][64]
    const float* __restrict__ Whh1,
    const float* __restrict__ bih1, const float* __restrict__ bhh1,
    const float* __restrict__ Wih2,
    const float* __restrict__ Whh2,
    const float* __restrict__ bih2, const float* __restrict__ bhh2,
    const float* __restrict__ Wout,  // [7][64]
    const float* __restrict__ bout,  // [7]
    float* __restrict__ out)         // [B][7]
{
    __shared__ __attribute__((aligned(16))) _Float16 xp[2][8 * 64];
    __shared__ __attribute__((aligned(16))) _Float16 h0p[8 * 64];
    __shared__ __attribute__((aligned(16))) _Float16 h1p[8 * 64];
    __shared__ __attribute__((aligned(16))) _Float16 h2p[8 * 64];
    __shared__ __attribute__((aligned(16))) float gt0[8 * NG];
    __shared__ __attribute__((aligned(16))) float gt1[8 * NG];
    __shared__ __attribute__((aligned(16))) float gt2[8 * NG];
    __shared__ __attribute__((aligned(16))) float hf[8 * HID];

    const int tid  = threadIdx.x;
    const int lane = tid & 63;
    const int wid  = tid >> 6;          // 0..15: N-tile index
    const int ncol = wid * 16 + (lane & 15);
    const int ksub = (lane >> 4) & 3;   // k-subgroup of 8
    const int arow = lane & 15;
    const int b0   = blockIdx.x * CB;

    // ---- weight fragments: 1-term fp16, all 3 layers resident (44 VGPR) ----
    const int k0 = ksub * 8;
    f16x8 WI0 = {0,0,0,0,0,0,0,0};
    if (k0 < 16) WI0 = ldw16(Wih0 + ncol * 16 + k0);
    const f16x8 WH00 = ldw16(Whh0 + ncol * HID + k0);
    const f16x8 WH01 = ldw16(Whh0 + ncol * HID + 32 + k0);
    const f16x8 WI10 = ldw16(Wih1 + ncol * HID + k0);
    const f16x8 WI11 = ldw16(Wih1 + ncol * HID + 32 + k0);
    const f16x8 WH10 = ldw16(Whh1 + ncol * HID + k0);
    const f16x8 WH11 = ldw16(Whh1 + ncol * HID + 32 + k0);
    const f16x8 WI20 = ldw16(Wih2 + ncol * HID + k0);
    const f16x8 WI21 = ldw16(Wih2 + ncol * HID + 32 + k0);
    const f16x8 WH20 = ldw16(Whh2 + ncol * HID + k0);
    const f16x8 WH21 = ldw16(Whh2 + ncol * HID + 32 + k0);
    const float bias0 = bih0[ncol] + bhh0[ncol];
    const float bias1 = bih1[ncol] + bhh1[ncol];
    const float bias2 = bih2[ncol] + bhh2[ncol];

    // ---- zero planes (xp: 512 u32; h planes: 256 u32 each) ----
    if (tid < 512) ((unsigned*)xp)[tid] = 0;
    else if (tid < 768) ((unsigned*)h0p)[tid - 512] = 0;
    if (tid >= 768) ((unsigned*)h1p)[tid - 768] = 0;
    if (tid < 256) ((unsigned*)h2p)[tid] = 0;
    __syncthreads();

    // ---- prologue: stage x(0)->buf0, x(1)->buf1 (threads 512-639) ----
    const int sidx = tid - 512;                 // staging index
    const int sbx = (sidx >> 4) & 7, sk = sidx & 15;
    const bool isStg = (tid >= 512) && (tid < 640);
    if (isStg) {
        #pragma unroll
        for (int s = 0; s < 2; ++s) {
            const float v = x0[(size_t)(b0 + sbx) * (T_STEPS * 16) + s * 16 + sk];
            pwr(xp[s], sbx, sk, (_Float16)v);
        }
    }
    __syncthreads();

    float cstA = 0.0f, cstB = 0.0f;   // tid<512: L0,L2 ; tid>=512: L1 (cstA)
    const float* xin = x0 + (size_t)(b0 + sbx) * (T_STEPS * 16) + 2 * 16 + sk;

    for (int it = 0; it < T_STEPS + 2; ++it) {
        const bool a0 = it < T_STEPS;
        const bool a1 = (it >= 1) && (it < T_STEPS + 1);
        const bool a2 = it >= 2;

        // ---- staging load issue: x(it+2) ----
        float pxn = 0.0f;
        if (isStg && it + 2 < T_STEPS) pxn = *xin;

        // ================= Phase A: MFMA for 3 layers =================
        {
            const f16x8 a00 = prd(h0p, arow, ksub);
            const f16x8 a01 = prd(h0p, arow, 4 + ksub);
            if (a0) {
                const f16x8 ax = prd(xp[it & 1], arow, ksub);
                f32x4 G = {bias0, bias0, bias0, bias0};
                G = MFMA16(ax, WI0, G);
                G = MFMA16(a00, WH00, G);
                G = MFMA16(a01, WH01, G);
                GTS_STORE(gt0, G);
            }
            const f16x8 a10 = prd(h1p, arow, ksub);
            const f16x8 a11 = prd(h1p, arow, 4 + ksub);
            if (a1) {
                f32x4 G = {bias1, bias1, bias1, bias1};
                G = MFMA16(a00, WI10, G);
                G = MFMA16(a01, WI11, G);
                G = MFMA16(a10, WH10, G);
                G = MFMA16(a11, WH11, G);
                GTS_STORE(gt1, G);
            }
            if (a2) {
                const f16x8 a20 = prd(h2p, arow, ksub);
                const f16x8 a21 = prd(h2p, arow, 4 + ksub);
                f32x4 G = {bias2, bias2, bias2, bias2};
                G = MFMA16(a10, WI20, G);
                G = MFMA16(a11, WI21, G);
                G = MFMA16(a20, WH20, G);
                G = MFMA16(a21, WH21, G);
                GTS_STORE(gt2, G);
            }
        }
        __syncthreads();

        // ================= Phase B: cells + staging =================
        if (tid < 512) {
            const int b = tid >> 6, u = tid & 63;
            float h;
            if (a0) CELL(gt0, cstA, h0p, b, u, h);
            if (a2) {
                CELL(gt2, cstB, h2p, b, u, h);
                if (it == T_STEPS + 1) hf[b * HID + u] = h;
            }
        } else {
            const int b = (tid - 512) >> 6, u = tid & 63;
            float h;
            if (a1) CELL(gt1, cstA, h1p, b, u, h);
            if (isStg && it + 2 < T_STEPS) pwr(xp[it & 1], sbx, sk, (_Float16)pxn);
        }
        __syncthreads();

        xin += 16;
    }

    // ---- head: out = h2[T-1] @ Wout^T + bout ----
    if (tid < 7 * CB) {
        const int b = tid / 7, o = tid % 7;
        float a = bout[o];
        #pragma unroll
        for (int k = 0; k < HID; ++k)
            a = fmaf(hf[b * HID + k], Wout[o * HID + k], a);
        out[(b0 + b) * 7 + o] = a;
    }
}

extern "C" void kernel_launch(void* const* d_in, const int* in_sizes, int n_in,
                              void* d_out, int out_size, void* d_ws, size_t ws_size,
                              hipStream_t stream) {
    const float* x    = (const float*)d_in[0];
    const float* Wih0 = (const float*)d_in[1];
    const float* Whh0 = (const float*)d_in[2];
    const float* bih0 = (const float*)d_in[3];
    const float* bhh0 = (const float*)d_in[4];
    const float* Wih1 = (const float*)d_in[5];
    const float* Whh1 = (const float*)d_in[6];
    const float* bih1 = (const float*)d_in[7];
    const float* bhh1 = (const float*)d_in[8];
    const float* Wih2 = (const float*)d_in[9];
    const float* Whh2 = (const float*)d_in[10];
    const float* bih2 = (const float*)d_in[11];
    const float* bhh2 = (const float*)d_in[12];
    const float* Wout = (const float*)d_in[13];
    const float* bout = (const float*)d_in[14];
    float* out = (float*)d_out;

    lstm3_fused<<<dim3(BATCH / CB), dim3(NTHR), 0, stream>>>(
        x, Wih0, Whh0, bih0, bhh0,
        Wih1, Whh1, bih1, bhh1,
        Wih2, Whh2, bih2, bhh2,
        Wout, bout, out);
}